// Round 13
// baseline (360.456 us; speedup 1.0000x reference)
//
#include <hip/hip_runtime.h>
#include <hip/hip_bf16.h>
#include <hip/hip_cooperative_groups.h>
#include <cstdint>

#define CIN 128
#define NH 8
#define CH 32

typedef short bf16x8 __attribute__((ext_vector_type(8)));
typedef short bf16x4 __attribute__((ext_vector_type(4)));
typedef float f32x4 __attribute__((ext_vector_type(4)));

__device__ __forceinline__ short f2bf(float f) {
  union { float f; unsigned u; } v; v.f = f;
  unsigned r = (v.u + 0x7FFFu + ((v.u >> 16) & 1u)) >> 16;   // RNE
  return (short)r;
}
__device__ __forceinline__ float bf2f(short s) {
  union { unsigned u; float f; } v; v.u = ((unsigned)(unsigned short)s) << 16;
  return v.f;
}
__device__ __forceinline__ unsigned pk2bf(float a, float b) {
  union { __hip_bfloat162 h; unsigned u; } cv;
  cv.h = __float22bfloat162_rn(make_float2(a, b));
  return cv.u;
}

// ---------------- standalone prep (FALLBACK ONLY, R12 verbatim) ----------------
__global__ __launch_bounds__(256) void prep(
    const float* __restrict__ Wq, const float* __restrict__ Wk,
    const float* __restrict__ Wv, const float* __restrict__ Wg,
    const float* __restrict__ Wo,
    const uint4* __restrict__ mask,
    short* __restrict__ WT, short* __restrict__ WoT,
    unsigned int* __restrict__ flag)
{
  const int b = blockIdx.x;
  const int tid = threadIdx.x;
  if (b < 40) {
    __shared__ short tile[64 * 68];
    const int rr = tid >> 4;
    const int cc = tid & 15;
    if (b < 32) {
      const int seg = b >> 3, sub = b & 7, kt = sub >> 2, nt = sub & 3;
      const int k0 = kt * 64, n0 = nt * 64;
      const float* W = (seg == 0) ? Wq : (seg == 1) ? Wk : (seg == 2) ? Wv : Wg;
      const float qs = (seg == 0) ? 0.17677669529663689f : 1.0f;
#pragma unroll
      for (int p = 0; p < 4; ++p) {
        int r = p * 16 + rr;
        float4 a = *(const float4*)(W + (size_t)(k0 + r) * 256 + n0 + cc * 4);
        tile[r * 68 + cc * 4 + 0] = f2bf(a.x * qs);
        tile[r * 68 + cc * 4 + 1] = f2bf(a.y * qs);
        tile[r * 68 + cc * 4 + 2] = f2bf(a.z * qs);
        tile[r * 68 + cc * 4 + 3] = f2bf(a.w * qs);
      }
      __syncthreads();
#pragma unroll
      for (int p = 0; p < 4; ++p) {
        int rn = p * 16 + rr;
        bf16x4 v;
        v[0] = tile[(cc * 4 + 0) * 68 + rn];
        v[1] = tile[(cc * 4 + 1) * 68 + rn];
        v[2] = tile[(cc * 4 + 2) * 68 + rn];
        v[3] = tile[(cc * 4 + 3) * 68 + rn];
        *(bf16x4*)(WT + (size_t)(seg * 256 + n0 + rn) * 128 + k0 + cc * 4) = v;
      }
    } else {
      const int sub = b - 32, kt = sub >> 1, nt = sub & 1;
      const int k0 = kt * 64, n0 = nt * 64;
#pragma unroll
      for (int p = 0; p < 4; ++p) {
        int r = p * 16 + rr;
        float4 a = *(const float4*)(Wo + (size_t)(k0 + r) * 128 + n0 + cc * 4);
        tile[r * 68 + cc * 4 + 0] = f2bf(a.x);
        tile[r * 68 + cc * 4 + 1] = f2bf(a.y);
        tile[r * 68 + cc * 4 + 2] = f2bf(a.z);
        tile[r * 68 + cc * 4 + 3] = f2bf(a.w);
      }
      __syncthreads();
#pragma unroll
      for (int p = 0; p < 4; ++p) {
        int rn = p * 16 + rr;
        bf16x4 v;
        v[0] = tile[(cc * 4 + 0) * 68 + rn];
        v[1] = tile[(cc * 4 + 1) * 68 + rn];
        v[2] = tile[(cc * 4 + 2) * 68 + rn];
        v[3] = tile[(cc * 4 + 3) * 68 + rn];
        *(bf16x4*)(WoT + (size_t)(n0 + rn) * 256 + k0 + cc * 4) = v;
      }
    }
  } else {
    __shared__ int viol;
    if (tid == 0) viol = 0;
    __syncthreads();
    int v = 0;
#pragma unroll
    for (int j = 0; j < 16; ++j) {
      uint4 w = mask[j * 256 + tid];
      v |= (w.x > 1u) | (w.y > 1u) | (w.z > 1u) | (w.w > 1u);
    }
    if (v) atomicOr(&viol, 1);
    __syncthreads();
    if (tid == 0) *flag = viol ? 0u : 1u;
  }
}

// ---------------- single-launch mega kernel: prep + grid.sync + fused body ------------
// do_prep=1 (cooperative): blocks 0..39 transpose weight tiles (xl as LDS scratch),
// block 40 mask-detect, then __threadfence + grid.sync + __threadfence (release/acquire
// across per-XCD L2s), then R12's fused body VERBATIM (measured 163 us, VGPR 116).
// do_prep=0 (fallback, regular launch after standalone prep): skip straight to body.
// LDS kept ~129 KB ON PURPOSE (allocator sees 1-block/CU cap -> free registers;
// R8/R10/R11: small LDS -> phantom-occupancy VGPR cap -> rematerialization storm).
__global__ __launch_bounds__(512) void fused_all(
    const float* __restrict__ x, short* __restrict__ WT,
    short* __restrict__ WoT, const float* __restrict__ bias,
    const float* __restrict__ bg, const float* __restrict__ bo,
    const void* __restrict__ maskraw, unsigned int* __restrict__ flagp,
    const float* __restrict__ Wq, const float* __restrict__ Wk,
    const float* __restrict__ Wv, const float* __restrict__ Wg,
    const float* __restrict__ Wo, float* __restrict__ out, int do_prep)
{
  __shared__ __align__(16) short xl[256 * 136];   // 69632 B; prep tile scratch pre-sync
  __shared__ __align__(16) short kL[256 * 40];    // 20480 B [key][chan]
  __shared__ __align__(16) short vL[32 * 264];    // 16896 B [chan][key]
  __shared__ __align__(16) short qL[256 * 40];    // 20480 B [q][chan]; reused as oL
  __shared__ float lL[256];
  __shared__ unsigned int scratch[8];
  __shared__ int viol;

  const int tid = threadIdx.x;
  const int srow = blockIdx.x;
  const int lane = tid & 63, w = tid >> 6;
  const int g = lane >> 4, c16 = lane & 15;
  const int myrow = w * 32;

  if (do_prep) {
    const int b = blockIdx.x;
    if (b < 40) {
      short* tile = xl;                 // 4352 shorts used
      const int rr = tid >> 4;          // 0..31 (512 thr)
      const int cc = tid & 15;
      if (b < 32) {
        const int seg = b >> 3, sub = b & 7, kt = sub >> 2, nt = sub & 3;
        const int k0 = kt * 64, n0 = nt * 64;
        const float* W = (seg == 0) ? Wq : (seg == 1) ? Wk : (seg == 2) ? Wv : Wg;
        const float qs = (seg == 0) ? 0.17677669529663689f : 1.0f;
#pragma unroll
        for (int p = 0; p < 2; ++p) {
          int r = p * 32 + rr;
          float4 a = *(const float4*)(W + (size_t)(k0 + r) * 256 + n0 + cc * 4);
          tile[r * 68 + cc * 4 + 0] = f2bf(a.x * qs);
          tile[r * 68 + cc * 4 + 1] = f2bf(a.y * qs);
          tile[r * 68 + cc * 4 + 2] = f2bf(a.z * qs);
          tile[r * 68 + cc * 4 + 3] = f2bf(a.w * qs);
        }
        __syncthreads();
#pragma unroll
        for (int p = 0; p < 2; ++p) {
          int rn = p * 32 + rr;
          bf16x4 v;
          v[0] = tile[(cc * 4 + 0) * 68 + rn];
          v[1] = tile[(cc * 4 + 1) * 68 + rn];
          v[2] = tile[(cc * 4 + 2) * 68 + rn];
          v[3] = tile[(cc * 4 + 3) * 68 + rn];
          *(bf16x4*)(WT + (size_t)(seg * 256 + n0 + rn) * 128 + k0 + cc * 4) = v;
        }
      } else {
        const int sub = b - 32, kt = sub >> 1, nt = sub & 1;
        const int k0 = kt * 64, n0 = nt * 64;
#pragma unroll
        for (int p = 0; p < 2; ++p) {
          int r = p * 32 + rr;
          float4 a = *(const float4*)(Wo + (size_t)(k0 + r) * 128 + n0 + cc * 4);
          tile[r * 68 + cc * 4 + 0] = f2bf(a.x);
          tile[r * 68 + cc * 4 + 1] = f2bf(a.y);
          tile[r * 68 + cc * 4 + 2] = f2bf(a.z);
          tile[r * 68 + cc * 4 + 3] = f2bf(a.w);
        }
        __syncthreads();
#pragma unroll
        for (int p = 0; p < 2; ++p) {
          int rn = p * 32 + rr;
          bf16x4 v;
          v[0] = tile[(cc * 4 + 0) * 68 + rn];
          v[1] = tile[(cc * 4 + 1) * 68 + rn];
          v[2] = tile[(cc * 4 + 2) * 68 + rn];
          v[3] = tile[(cc * 4 + 3) * 68 + rn];
          *(bf16x4*)(WoT + (size_t)(n0 + rn) * 256 + k0 + cc * 4) = v;
        }
      }
    } else if (b == 40) {
      if (tid == 0) viol = 0;
      __syncthreads();
      int v = 0;
      const uint4* m4 = (const uint4*)maskraw;
#pragma unroll
      for (int j = 0; j < 8; ++j) {
        uint4 wv = m4[j * 512 + tid];
        v |= (wv.x > 1u) | (wv.y > 1u) | (wv.z > 1u) | (wv.w > 1u);
      }
      if (v) atomicOr(&viol, 1);
      __syncthreads();
      if (tid == 0) *flagp = viol ? 0u : 1u;
    }
    __threadfence();                       // release: WT/WoT/flag -> device scope
    cooperative_groups::this_grid().sync();
    __threadfence();                       // acquire: invalidate stale lines
  }

  // ================= R12 fused body (verbatim) =================
  const unsigned int fl = *(volatile const unsigned int*)flagp;
  if (tid < 256) {
    int mv = fl ? ((const int*)maskraw)[srow * 256 + tid]
                : (int)((const unsigned char*)maskraw)[srow * 256 + tid];
    unsigned long long bb = __ballot(mv != 0);
    if (lane == 0) {
      scratch[w * 2 + 0] = (unsigned int)bb;
      scratch[w * 2 + 1] = (unsigned int)(bb >> 32);
    }
  }

  {
    const float* xs = x + (size_t)srow * 256 * 128;
#pragma unroll
    for (int it = 0; it < 16; ++it) {
      int idx = it * 512 + tid;          // float4 index
      int row = idx >> 5, c4 = idx & 31;
      float4 a = *(const float4*)(xs + (size_t)idx * 4);
      union { unsigned u[2]; bf16x4 v; } pu;
      pu.u[0] = pk2bf(a.x, a.y);
      pu.u[1] = pk2bf(a.z, a.w);
      *(bf16x4*)&xl[row * 136 + c4 * 4] = pu.v;
    }
  }
  __syncthreads();

  unsigned int mb[8];
#pragma unroll
  for (int j = 0; j < 8; ++j) mb[j] = scratch[j];

  const f32x4 zero4 = {0.f, 0.f, 0.f, 0.f};
  f32x4 acc_out[2][8];
#pragma unroll
  for (int qt = 0; qt < 2; ++qt)
#pragma unroll
    for (int ct = 0; ct < 8; ++ct) acc_out[qt][ct] = zero4;

#pragma unroll 1
  for (int h = 0; h < 8; ++h) {
    f32x4 ga[2][2];
    // K: mfma(Wf,xf) -> kL[key][chan]
    {
      f32x4 acc[2][2];
#pragma unroll
      for (int ct = 0; ct < 2; ++ct)
#pragma unroll
        for (int rt = 0; rt < 2; ++rt) acc[ct][rt] = zero4;
#pragma unroll
      for (int kk = 0; kk < 4; ++kk) {
        bf16x8 wf[2], xf[2];
#pragma unroll
        for (int ct = 0; ct < 2; ++ct)
          wf[ct] = *(const bf16x8*)(WT + (size_t)(256 + h * CH + ct * 16 + c16) * 128 + kk * 32 + g * 8);
#pragma unroll
        for (int rt = 0; rt < 2; ++rt)
          xf[rt] = *(const bf16x8*)&xl[(myrow + rt * 16 + c16) * 136 + kk * 32 + g * 8];
#pragma unroll
        for (int ct = 0; ct < 2; ++ct)
#pragma unroll
          for (int rt = 0; rt < 2; ++rt)
            acc[ct][rt] = __builtin_amdgcn_mfma_f32_16x16x32_bf16(wf[ct], xf[rt], acc[ct][rt], 0, 0, 0);
      }
#pragma unroll
      for (int ct = 0; ct < 2; ++ct)
#pragma unroll
        for (int rt = 0; rt < 2; ++rt) {
          union { unsigned u[2]; bf16x4 v; } pu;
          pu.u[0] = pk2bf(acc[ct][rt][0], acc[ct][rt][1]);
          pu.u[1] = pk2bf(acc[ct][rt][2], acc[ct][rt][3]);
          *(bf16x4*)&kL[(myrow + rt * 16 + c16) * 40 + ct * 16 + g * 4] = pu.v;
        }
    }
    // V: mfma(xf,Wf) -> vL[chan][key]
    {
      f32x4 acc[2][2];
#pragma unroll
      for (int rt = 0; rt < 2; ++rt)
#pragma unroll
        for (int ct = 0; ct < 2; ++ct) acc[rt][ct] = zero4;
#pragma unroll
      for (int kk = 0; kk < 4; ++kk) {
        bf16x8 wf[2], xf[2];
#pragma unroll
        for (int ct = 0; ct < 2; ++ct)
          wf[ct] = *(const bf16x8*)(WT + (size_t)(512 + h * CH + ct * 16 + c16) * 128 + kk * 32 + g * 8);
#pragma unroll
        for (int rt = 0; rt < 2; ++rt)
          xf[rt] = *(const bf16x8*)&xl[(myrow + rt * 16 + c16) * 136 + kk * 32 + g * 8];
#pragma unroll
        for (int rt = 0; rt < 2; ++rt)
#pragma unroll
          for (int ct = 0; ct < 2; ++ct)
            acc[rt][ct] = __builtin_amdgcn_mfma_f32_16x16x32_bf16(xf[rt], wf[ct], acc[rt][ct], 0, 0, 0);
      }
#pragma unroll
      for (int rt = 0; rt < 2; ++rt)
#pragma unroll
        for (int ct = 0; ct < 2; ++ct) {
          union { unsigned u[2]; bf16x4 v; } pu;
          pu.u[0] = pk2bf(acc[rt][ct][0], acc[rt][ct][1]);
          pu.u[1] = pk2bf(acc[rt][ct][2], acc[rt][ct][3]);
          *(bf16x4*)&vL[(size_t)(ct * 16 + c16) * 264 + myrow + rt * 16 + g * 4] = pu.v;
        }
    }
    // Q -> qL[q][chan]
    {
      f32x4 acc[2][2];
#pragma unroll
      for (int ct = 0; ct < 2; ++ct)
#pragma unroll
        for (int rt = 0; rt < 2; ++rt) acc[ct][rt] = zero4;
#pragma unroll
      for (int kk = 0; kk < 4; ++kk) {
        bf16x8 wf[2], xf[2];
#pragma unroll
        for (int ct = 0; ct < 2; ++ct)
          wf[ct] = *(const bf16x8*)(WT + (size_t)(0 + h * CH + ct * 16 + c16) * 128 + kk * 32 + g * 8);
#pragma unroll
        for (int rt = 0; rt < 2; ++rt)
          xf[rt] = *(const bf16x8*)&xl[(myrow + rt * 16 + c16) * 136 + kk * 32 + g * 8];
#pragma unroll
        for (int ct = 0; ct < 2; ++ct)
#pragma unroll
          for (int rt = 0; rt < 2; ++rt)
            acc[ct][rt] = __builtin_amdgcn_mfma_f32_16x16x32_bf16(wf[ct], xf[rt], acc[ct][rt], 0, 0, 0);
      }
#pragma unroll
      for (int ct = 0; ct < 2; ++ct)
#pragma unroll
        for (int rt = 0; rt < 2; ++rt) {
          union { unsigned u[2]; bf16x4 v; } pu;
          pu.u[0] = pk2bf(acc[ct][rt][0], acc[ct][rt][1]);
          pu.u[1] = pk2bf(acc[ct][rt][2], acc[ct][rt][3]);
          *(bf16x4*)&qL[(myrow + rt * 16 + c16) * 40 + ct * 16 + g * 4] = pu.v;
        }
    }
    // G -> registers (O-fragment layout)
    {
#pragma unroll
      for (int rt = 0; rt < 2; ++rt)
#pragma unroll
        for (int ct = 0; ct < 2; ++ct) ga[rt][ct] = zero4;
#pragma unroll
      for (int kk = 0; kk < 4; ++kk) {
        bf16x8 wf[2], xf[2];
#pragma unroll
        for (int ct = 0; ct < 2; ++ct)
          wf[ct] = *(const bf16x8*)(WT + (size_t)(768 + h * CH + ct * 16 + c16) * 128 + kk * 32 + g * 8);
#pragma unroll
        for (int rt = 0; rt < 2; ++rt)
          xf[rt] = *(const bf16x8*)&xl[(myrow + rt * 16 + c16) * 136 + kk * 32 + g * 8];
#pragma unroll
        for (int rt = 0; rt < 2; ++rt)
#pragma unroll
          for (int ct = 0; ct < 2; ++ct)
            ga[rt][ct] = __builtin_amdgcn_mfma_f32_16x16x32_bf16(xf[rt], wf[ct], ga[rt][ct], 0, 0, 0);
      }
    }
    __syncthreads();   // A

    const int qb = myrow;
    bf16x8 qf[2];
#pragma unroll
    for (int qt = 0; qt < 2; ++qt)
      qf[qt] = *(const bf16x8*)&qL[(qb + qt * 16 + c16) * 40 + g * 8];

    float l_[2] = {0.f, 0.f};
    f32x4 O[2][2];
#pragma unroll
    for (int qt = 0; qt < 2; ++qt) { O[qt][0] = zero4; O[qt][1] = zero4; }

    const float* bh = bias + (size_t)h * 65536;

#pragma unroll 1
    for (int ch = 0; ch < 8; ++ch) {
      float4 bb4[2][2];
#pragma unroll
      for (int kt = 0; kt < 2; ++kt)
#pragma unroll
        for (int qt = 0; qt < 2; ++qt)
          bb4[kt][qt] = *(const float4*)(bh + (size_t)(qb + qt * 16 + c16) * 256 +
                                         ch * 32 + kt * 16 + g * 4);

#pragma unroll
      for (int kt = 0; kt < 2; ++kt) {
        bf16x8 kf = *(const bf16x8*)&kL[(ch * 32 + kt * 16 + c16) * 40 + g * 8];
        bf16x4 vlo = *(const bf16x4*)&vL[(size_t)c16 * 264 + ch * 32 + kt * 16 + g * 4];
        bf16x4 vhi = *(const bf16x4*)&vL[(size_t)(16 + c16) * 264 + ch * 32 + kt * 16 + g * 4];
        const unsigned nib = (mb[ch] >> (kt * 16 + g * 4)) & 0xFu;
        float em[4];
#pragma unroll
        for (int i = 0; i < 4; ++i) em[i] = ((nib >> i) & 1u) ? 1.f : 0.f;
#pragma unroll
        for (int qt = 0; qt < 2; ++qt) {
          f32x4 S = __builtin_amdgcn_mfma_f32_16x16x32_bf16(kf, qf[qt], zero4, 0, 0, 0);
          float p0 = em[0] * __expf(fminf(S[0] + bb4[kt][qt].x, 85.f));
          float p1 = em[1] * __expf(fminf(S[1] + bb4[kt][qt].y, 85.f));
          float p2 = em[2] * __expf(fminf(S[2] + bb4[kt][qt].z, 85.f));
          float p3 = em[3] * __expf(fminf(S[3] + bb4[kt][qt].w, 85.f));
          l_[qt] += (p0 + p1) + (p2 + p3);
          union { unsigned u[2]; bf16x4 v; } pu;
          pu.u[0] = pk2bf(p0, p1);
          pu.u[1] = pk2bf(p2, p3);
          O[qt][0] = __builtin_amdgcn_mfma_f32_16x16x16bf16_1k(pu.v, vlo, O[qt][0], 0, 0, 0);
          O[qt][1] = __builtin_amdgcn_mfma_f32_16x16x16bf16_1k(pu.v, vhi, O[qt][1], 0, 0, 0);
        }
      }
    }

#pragma unroll
    for (int qt = 0; qt < 2; ++qt) {
      float v = l_[qt];
      v += __shfl_xor(v, 16);
      v += __shfl_xor(v, 32);
      if (lane < 16) lL[myrow + qt * 16 + c16] = v;
    }

    {
      float bgl0 = bg[h * CH + c16];
      float bgl1 = bg[h * CH + 16 + c16];
#pragma unroll
      for (int qt = 0; qt < 2; ++qt)
#pragma unroll
        for (int i = 0; i < 4; ++i) {
          int row = qb + qt * 16 + g * 4 + i;
          float inv = 1.f / lL[myrow + qt * 16 + g * 4 + i];
          float g0 = 1.f / (1.f + __expf(-(ga[qt][0][i] + bgl0)));
          float g1 = 1.f / (1.f + __expf(-(ga[qt][1][i] + bgl1)));
          qL[row * 40 + c16]      = f2bf(O[qt][0][i] * inv * g0);
          qL[row * 40 + 16 + c16] = f2bf(O[qt][1][i] * inv * g1);
        }
    }

    {
      bf16x8 wo[8];
#pragma unroll
      for (int ct = 0; ct < 8; ++ct)
        wo[ct] = *(const bf16x8*)(WoT + (size_t)(ct * 16 + c16) * 256 + h * 32 + g * 8);
#pragma unroll
      for (int qt = 0; qt < 2; ++qt) {
        bf16x8 of = *(const bf16x8*)&qL[(qb + qt * 16 + c16) * 40 + g * 8];
#pragma unroll
        for (int ct = 0; ct < 8; ++ct)
          acc_out[qt][ct] = __builtin_amdgcn_mfma_f32_16x16x32_bf16(of, wo[ct], acc_out[qt][ct], 0, 0, 0);
      }
    }
    __syncthreads();   // B
  }

#pragma unroll
  for (int ct = 0; ct < 8; ++ct) {
    float bv = bo[ct * 16 + c16];
#pragma unroll
    for (int qt = 0; qt < 2; ++qt)
#pragma unroll
      for (int i = 0; i < 4; ++i)
        out[((size_t)srow * 256 + myrow + qt * 16 + g * 4 + i) * 128 + ct * 16 + c16] =
            acc_out[qt][ct][i] + bv;
  }
}

extern "C" void kernel_launch(void* const* d_in, const int* in_sizes, int n_in,
                              void* d_out, int out_size, void* d_ws, size_t ws_size,
                              hipStream_t stream) {
  const float* x    = (const float*)d_in[0];
  const float* bias = (const float*)d_in[1];
  const void*  mask = d_in[2];
  const float* Wq   = (const float*)d_in[3];
  const float* Wk   = (const float*)d_in[4];
  const float* Wv   = (const float*)d_in[5];
  const float* Wo   = (const float*)d_in[6];
  const float* bo   = (const float*)d_in[7];
  const float* Wg   = (const float*)d_in[8];
  const float* bg   = (const float*)d_in[9];
  float* out = (float*)d_out;

  // ws: [flag 256B][WT 256KB][WoT 64KB]
  unsigned int* flag = (unsigned int*)d_ws;
  short* WT  = (short*)((char*)d_ws + 256);
  short* WoT = WT + 131072;

  int do_prep = 1;
  void* kargs[] = {
    (void*)&x, (void*)&WT, (void*)&WoT, (void*)&bias, (void*)&bg, (void*)&bo,
    (void*)&mask, (void*)&flag, (void*)&Wq, (void*)&Wk, (void*)&Wv, (void*)&Wg,
    (void*)&Wo, (void*)&out, (void*)&do_prep
  };
  hipError_t err = hipLaunchCooperativeKernel(
      reinterpret_cast<void*>(fused_all), dim3(256), dim3(512), kargs, 0, stream);
  if (err != hipSuccess) {
    // fallback: R12 two-launch pipeline (identical numerics)
    prep<<<41, 256, 0, stream>>>(Wq, Wk, Wv, Wg, Wo, (const uint4*)mask,
                                 WT, WoT, flag);
    fused_all<<<256, 512, 0, stream>>>(x, WT, WoT, bias, bg, bo,
                                       mask, flag, Wq, Wk, Wv, Wg, Wo, out, 0);
  }
}